// Round 2
// baseline (474.580 us; speedup 1.0000x reference)
//
#include <hip/hip_runtime.h>

typedef unsigned short u16;
typedef short bf16x8 __attribute__((ext_vector_type(8)));
typedef float f32x4 __attribute__((ext_vector_type(4)));

__device__ __forceinline__ float bf2f(u16 u) {
    union { unsigned int i; float f; } v; v.i = ((unsigned int)u) << 16; return v.f;
}
__device__ __forceinline__ u16 f2bf(float f) {
    union { float f; unsigned int i; } v; v.f = f;
    unsigned int r = v.i + 0x7fffu + ((v.i >> 16) & 1u);
    return (u16)(r >> 16);
}

// ---------------------------------------------------------------------------
// fp32 -> bf16 transpose: out[c][r] = (bf16)in[r][c].  blockIdx.z = batch.
// ---------------------------------------------------------------------------
__global__ __launch_bounds__(256) void transpose_f32_bf16(const float* __restrict__ in,
                                                          u16* __restrict__ out,
                                                          int R, int C) {
    __shared__ u16 tile[64][65];
    int c0 = blockIdx.x * 64, r0 = blockIdx.y * 64;
    in  += (size_t)blockIdx.z * R * C;
    out += (size_t)blockIdx.z * R * C;
    for (int i = threadIdx.x; i < 4096; i += 256) {
        int r = i >> 6, c = i & 63;
        tile[r][c] = f2bf(in[(size_t)(r0 + r) * C + c0 + c]);
    }
    __syncthreads();
    for (int i = threadIdx.x; i < 4096; i += 256) {
        int r = i >> 6, c = i & 63;   // r: col-of-in index, c: row-of-in index
        out[(size_t)(c0 + r) * R + r0 + c] = tile[c][r];
    }
}

// ---------------------------------------------------------------------------
// bf16 transpose (for V -> Vt): out[c][r] = in[r][c].  blockIdx.z = batch.
// ---------------------------------------------------------------------------
__global__ __launch_bounds__(256) void transpose_bf16(const u16* __restrict__ in,
                                                      u16* __restrict__ out,
                                                      int R, int C) {
    __shared__ u16 tile[64][65];
    int c0 = blockIdx.x * 64, r0 = blockIdx.y * 64;
    size_t boff = (size_t)blockIdx.z * R * C;
    in += boff; out += boff;
    for (int i = threadIdx.x; i < 4096; i += 256) {
        int r = i >> 6, c = i & 63;
        tile[r][c] = in[(size_t)(r0 + r) * C + c0 + c];
    }
    __syncthreads();
    for (int i = threadIdx.x; i < 4096; i += 256) {
        int r = i >> 6, c = i & 63;
        out[(size_t)(c0 + r) * R + r0 + c] = tile[c][r];
    }
}

// ---------------------------------------------------------------------------
// LayerNorm over 1024 cols (fp32 in, bf16 out), one row per block.
// ---------------------------------------------------------------------------
__global__ __launch_bounds__(256) void ln_f32(const float* __restrict__ x,
                                              const float* __restrict__ g,
                                              const float* __restrict__ be,
                                              u16* __restrict__ out) {
    int row = blockIdx.x, tid = threadIdx.x;
    int lane = tid & 63, wave = tid >> 6;
    const float* xr = x + (size_t)row * 1024 + tid * 4;
    float4 f4 = *(const float4*)xr;
    float v[4] = {f4.x, f4.y, f4.z, f4.w};
    float s1 = v[0] + v[1] + v[2] + v[3];
    float s2 = v[0]*v[0] + v[1]*v[1] + v[2]*v[2] + v[3]*v[3];
#pragma unroll
    for (int mm = 1; mm < 64; mm <<= 1) { s1 += __shfl_xor(s1, mm); s2 += __shfl_xor(s2, mm); }
    __shared__ float a1[4], a2[4];
    if (lane == 0) { a1[wave] = s1; a2[wave] = s2; }
    __syncthreads();
    s1 = a1[0] + a1[1] + a1[2] + a1[3];
    s2 = a2[0] + a2[1] + a2[2] + a2[3];
    float mean = s1 * (1.0f / 1024.0f);
    float var  = s2 * (1.0f / 1024.0f) - mean * mean;
    float rstd = rsqrtf(var + 1e-5f);
#pragma unroll
    for (int i = 0; i < 4; ++i) {
        int c = tid * 4 + i;
        float o = (v[i] - mean) * rstd * g[c] + be[c];
        out[(size_t)row * 1024 + c] = f2bf(o);
    }
}

// ---------------------------------------------------------------------------
// GEMM: C[M][N] = op(A[M][K] @ W[K][N] + bias [+ resid]), W given TRANSPOSED
// (WT [N][K], bf16). A bf16. bias/resid fp32. 128x128 tile per block (256
// thr, 4 waves 2x2, each 64x64 = 4x4 MFMA 16x16x32 tiles). BK=64. LDS rows
// padded to 72 elems (16B-aligned; 2-way bank aliasing is free).
// ACT=1: tanh-gelu.  RES=1: += fp32 residual.  OutT: float or u16(bf16).
// ---------------------------------------------------------------------------
template <int ACT, int RES, typename OutT>
__global__ __launch_bounds__(256) void gemm_kernel(const u16* __restrict__ A,
                                                   const u16* __restrict__ WT,
                                                   const float* __restrict__ bias,
                                                   const float* __restrict__ resid,
                                                   OutT* __restrict__ C,
                                                   int M, int N, int K) {
    __shared__ u16 lds_a[128 * 72];
    __shared__ u16 lds_b[128 * 72];
    int tid = threadIdx.x;
    int lane = tid & 63, wave = tid >> 6;
    int l16 = lane & 15, quad = lane >> 4;
    int wm = (wave >> 1) * 64, wn = (wave & 1) * 64;
    int m0 = blockIdx.y * 128, n0 = blockIdx.x * 128;
    f32x4 acc[4][4] = {};

    int stg_row = tid >> 3;          // 0..31
    int stg_c8  = (tid & 7) * 8;     // 16B chunk within 64-elem k-run

    for (int k0 = 0; k0 < K; k0 += 64) {
        __syncthreads();
#pragma unroll
        for (int it = 0; it < 4; ++it) {
            int row = stg_row + it * 32;
            *(uint4*)&lds_a[row * 72 + stg_c8] =
                *(const uint4*)&A[(size_t)(m0 + row) * K + k0 + stg_c8];
            *(uint4*)&lds_b[row * 72 + stg_c8] =
                *(const uint4*)&WT[(size_t)(n0 + row) * K + k0 + stg_c8];
        }
        __syncthreads();
#pragma unroll
        for (int s = 0; s < 2; ++s) {
            bf16x8 af[4], bfr[4];
#pragma unroll
            for (int i = 0; i < 4; ++i)
                af[i] = *(const bf16x8*)&lds_a[(wm + i * 16 + l16) * 72 + s * 32 + quad * 8];
#pragma unroll
            for (int j = 0; j < 4; ++j)
                bfr[j] = *(const bf16x8*)&lds_b[(wn + j * 16 + l16) * 72 + s * 32 + quad * 8];
#pragma unroll
            for (int i = 0; i < 4; ++i)
#pragma unroll
                for (int j = 0; j < 4; ++j)
                    acc[i][j] = __builtin_amdgcn_mfma_f32_16x16x32_bf16(af[i], bfr[j], acc[i][j], 0, 0, 0);
        }
    }

    // Epilogue. C/D layout: col = lane&15, row = quad*4 + reg.
#pragma unroll
    for (int j = 0; j < 4; ++j) {
        int col = n0 + wn + j * 16 + l16;
        float bv = bias[col];
#pragma unroll
        for (int i = 0; i < 4; ++i) {
            int rbase = m0 + wm + i * 16 + quad * 4;
#pragma unroll
            for (int r = 0; r < 4; ++r) {
                size_t idx = (size_t)(rbase + r) * N + col;
                float v = acc[i][j][r] + bv;
                if (ACT == 1) {
                    float u = v;
                    float y = 0.7978845608028654f * (u + 0.044715f * u * u * u);
                    float t = __expf(2.0f * y);
                    float th = 1.0f - 2.0f / (t + 1.0f);   // tanh(y)
                    v = 0.5f * u * (1.0f + th);
                }
                if (RES) v += resid[idx];
                if constexpr (sizeof(OutT) == 4) C[idx] = v;
                else                             C[idx] = f2bf(v);
            }
        }
    }
}

// ---------------------------------------------------------------------------
// Flash-style causal attention, Q==K (shared projection).
// grid: (qtile=32, head=16, batch=2). block: 256 = 4 waves, each wave owns
// 16 query rows. K/V tiles of 64 keys staged in LDS; V pre-transposed
// globally to Vt[b,h,d,s]. d=64: 2 MFMA k-steps per matmul.
// ---------------------------------------------------------------------------
__global__ __launch_bounds__(256) void attn_kernel(const u16* __restrict__ Q,
                                                   const u16* __restrict__ Vt,
                                                   u16* __restrict__ Out) {
    int qt = blockIdx.x, h = blockIdx.y, b = blockIdx.z;
    int tid = threadIdx.x;
    int lane = tid & 63, wave = tid >> 6;
    int l16 = lane & 15, quad = lane >> 4;

    __shared__ u16 k_lds[64 * 72];
    __shared__ u16 v_lds[64 * 72];
    __shared__ u16 p_lds[4][16 * 72];

    // Q fragments (A layout: m = lane&15, k = quad*8+j), pre-scaled by 1/8.
    int qrow = qt * 64 + wave * 16 + l16;
    const u16* qp = Q + ((size_t)b * 2048 + qrow) * 1024 + h * 64;
    bf16x8 qf[2];
#pragma unroll
    for (int s = 0; s < 2; ++s) {
        u16 tmp[8]; *(uint4*)tmp = *(const uint4*)&qp[s * 32 + quad * 8];
#pragma unroll
        for (int e = 0; e < 8; ++e) qf[s][e] = (short)f2bf(bf2f(tmp[e]) * 0.125f);
    }

    float mr[4] = {-1e30f, -1e30f, -1e30f, -1e30f};
    float lr[4] = {0.f, 0.f, 0.f, 0.f};
    f32x4 O[4] = {};

    int stg_r = tid >> 3, stg_c8 = (tid & 7) * 8;

    for (int kt = 0; kt <= qt; ++kt) {
        __syncthreads();
#pragma unroll
        for (int it = 0; it < 2; ++it) {
            int rr = stg_r + it * 32;
            *(uint4*)&k_lds[rr * 72 + stg_c8] =
                *(const uint4*)&Q[((size_t)b * 2048 + kt * 64 + rr) * 1024 + h * 64 + stg_c8];
            *(uint4*)&v_lds[rr * 72 + stg_c8] =
                *(const uint4*)&Vt[(((size_t)b * 16 + h) * 64 + rr) * 2048 + kt * 64 + stg_c8];
        }
        __syncthreads();

        // S = (Q/8) @ K^T : 16 x 64 per wave
        f32x4 S[4] = {};
#pragma unroll
        for (int s = 0; s < 2; ++s)
#pragma unroll
            for (int j = 0; j < 4; ++j) {
                bf16x8 kf = *(const bf16x8*)&k_lds[(j * 16 + l16) * 72 + s * 32 + quad * 8];
                S[j] = __builtin_amdgcn_mfma_f32_16x16x32_bf16(qf[s], kf, S[j], 0, 0, 0);
            }

        if (kt == qt) {  // causal mask, diagonal tile only
#pragma unroll
            for (int j = 0; j < 4; ++j) {
                int key = j * 16 + l16;
#pragma unroll
                for (int r = 0; r < 4; ++r)
                    if (key > wave * 16 + quad * 4 + r) S[j][r] = -1e30f;
            }
        }

        // online softmax (each row lives across the 16 lanes of a quad-group)
        float alpha[4];
#pragma unroll
        for (int r = 0; r < 4; ++r) {
            float mx = fmaxf(fmaxf(S[0][r], S[1][r]), fmaxf(S[2][r], S[3][r]));
#pragma unroll
            for (int mm = 1; mm < 16; mm <<= 1) mx = fmaxf(mx, __shfl_xor(mx, mm));
            float mnew = fmaxf(mr[r], mx);
            alpha[r] = __expf(mr[r] - mnew);
            mr[r] = mnew;
            float rs = 0.f;
#pragma unroll
            for (int j = 0; j < 4; ++j) {
                float p = __expf(S[j][r] - mnew);
                rs += p;
                p_lds[wave][(quad * 4 + r) * 72 + j * 16 + l16] = f2bf(p);
            }
#pragma unroll
            for (int mm = 1; mm < 16; mm <<= 1) rs += __shfl_xor(rs, mm);
            lr[r] = lr[r] * alpha[r] + rs;
        }
#pragma unroll
        for (int dj = 0; dj < 4; ++dj)
#pragma unroll
            for (int r = 0; r < 4; ++r) O[dj][r] *= alpha[r];

        // O += P @ V   (P read back in A layout; Vt rows give B layout)
#pragma unroll
        for (int s = 0; s < 2; ++s) {
            bf16x8 pf = *(const bf16x8*)&p_lds[wave][l16 * 72 + s * 32 + quad * 8];
#pragma unroll
            for (int dj = 0; dj < 4; ++dj) {
                bf16x8 vf = *(const bf16x8*)&v_lds[(dj * 16 + l16) * 72 + s * 32 + quad * 8];
                O[dj] = __builtin_amdgcn_mfma_f32_16x16x32_bf16(pf, vf, O[dj], 0, 0, 0);
            }
        }
    }

#pragma unroll
    for (int dj = 0; dj < 4; ++dj)
#pragma unroll
        for (int r = 0; r < 4; ++r) {
            int qg = qt * 64 + wave * 16 + quad * 4 + r;
            float o = O[dj][r] / lr[r];
            Out[((size_t)b * 2048 + qg) * 1024 + h * 64 + dj * 16 + l16] = f2bf(o);
        }
}

// ---------------------------------------------------------------------------
extern "C" void kernel_launch(void* const* d_in, const int* in_sizes, int n_in,
                              void* d_out, int out_size, void* d_ws, size_t ws_size,
                              hipStream_t stream) {
    // Reference dtypes are all float32.
    const float* x   = (const float*)d_in[0];
    const float* Wq  = (const float*)d_in[1];
    const float* bq  = (const float*)d_in[2];
    const float* Wv  = (const float*)d_in[3];
    const float* bv  = (const float*)d_in[4];
    const float* Wo  = (const float*)d_in[5];
    const float* bo  = (const float*)d_in[6];
    const float* W1  = (const float*)d_in[7];
    const float* b1  = (const float*)d_in[8];
    const float* W2  = (const float*)d_in[9];
    const float* b2  = (const float*)d_in[10];
    const float* g1  = (const float*)d_in[11];
    const float* be1 = (const float*)d_in[12];
    const float* g2  = (const float*)d_in[13];
    const float* be2 = (const float*)d_in[14];

    char* ws = (char*)d_ws;
    const size_t MB = 1 << 20;
    u16*   WqT = (u16*)(ws + 0  * MB);   // [1024][1024] bf16, 2 MB
    u16*   WvT = (u16*)(ws + 2  * MB);   // 2 MB
    u16*   WoT = (u16*)(ws + 4  * MB);   // 2 MB
    u16*   W1T = (u16*)(ws + 6  * MB);   // [4096][1024] bf16, 8 MB
    u16*   W2T = (u16*)(ws + 14 * MB);   // [1024][4096] bf16, 8 MB
    u16*   h1  = (u16*)(ws + 22 * MB);   // LN1 out / attn out, bf16, 8 MB
    u16*   Qb  = (u16*)(ws + 30 * MB);   // Q proj / h2, bf16, 8 MB
    u16*   V   = (u16*)(ws + 38 * MB);   // bf16, 8 MB (dead after step 4)
    u16*   Vt  = (u16*)(ws + 46 * MB);   // bf16, 8 MB (dead after step 5)
    float* x2  = (float*)(ws + 38 * MB); // fp32, 16 MB — overlays V/Vt after attn
    u16*   ff1 = (u16*)(ws + 54 * MB);   // bf16 [4096][4096], 32 MB, ends 86 MB

    // 1. weight transposes + bf16 downcast (WT[N][K])
    transpose_f32_bf16<<<dim3(16, 16, 1), 256, 0, stream>>>(Wq, WqT, 1024, 1024);
    transpose_f32_bf16<<<dim3(16, 16, 1), 256, 0, stream>>>(Wv, WvT, 1024, 1024);
    transpose_f32_bf16<<<dim3(16, 16, 1), 256, 0, stream>>>(Wo, WoT, 1024, 1024);
    transpose_f32_bf16<<<dim3(64, 16, 1), 256, 0, stream>>>(W1, W1T, 1024, 4096);
    transpose_f32_bf16<<<dim3(16, 64, 1), 256, 0, stream>>>(W2, W2T, 4096, 1024);

    // 2. h1 = LN1(x)
    ln_f32<<<4096, 256, 0, stream>>>(x, g1, be1, h1);

    // 3. Q = h1@Wq + bq ; V = h1@Wv + bv
    gemm_kernel<0, 0, u16><<<dim3(8, 32), 256, 0, stream>>>(h1, WqT, bq, nullptr, Qb, 4096, 1024, 1024);
    gemm_kernel<0, 0, u16><<<dim3(8, 32), 256, 0, stream>>>(h1, WvT, bv, nullptr, V, 4096, 1024, 1024);

    // 4. Vt[b,h,d,s] = per-batch transpose of V[b,s,(h d)]
    transpose_bf16<<<dim3(16, 32, 2), 256, 0, stream>>>(V, Vt, 2048, 1024);

    // 5. attention → h1 (reused as attn_out)
    attn_kernel<<<dim3(32, 16, 2), 256, 0, stream>>>(Qb, Vt, h1);

    // 6. x2 = x + attn_out@Wo + bo   (fp32)
    gemm_kernel<0, 1, float><<<dim3(8, 32), 256, 0, stream>>>(h1, WoT, bo, x, x2, 4096, 1024, 1024);

    // 7. h2 = LN2(x2)  (reuses Q buffer)
    ln_f32<<<4096, 256, 0, stream>>>(x2, g2, be2, Qb);

    // 8. ff1 = gelu(h2@W1 + b1)
    gemm_kernel<1, 0, u16><<<dim3(32, 32), 256, 0, stream>>>(Qb, W1T, b1, nullptr, ff1, 4096, 4096, 1024);

    // 9. out = x2 + ff1@W2 + b2  (fp32 out)
    gemm_kernel<0, 1, float><<<dim3(8, 32), 256, 0, stream>>>(ff1, W2T, b2, x2, (float*)d_out, 4096, 1024, 4096);
}